// Round 9
// baseline (575.908 us; speedup 1.0000x reference)
//
#include <hip/hip_runtime.h>
#include <stdint.h>

#define N_ITEMS   200000
#define N_USERS   16384
#define N_HIST    819200

typedef short bfrag8 __attribute__((ext_vector_type(8)));
typedef float ffrag4 __attribute__((ext_vector_type(4)));

__device__ __forceinline__ unsigned short f2bf(float f) {
    union { float f; unsigned int u; } v; v.f = f;
    unsigned int u = v.u;
    u += 0x7fffu + ((u >> 16) & 1u);   // round-to-nearest-even
    return (unsigned short)(u >> 16);
}

__device__ __forceinline__ ffrag4 mfma16(bfrag8 a, bfrag8 b, ffrag4 c) {
    return __builtin_amdgcn_mfma_f32_16x16x32_bf16(a, b, c, 0, 0, 0);
}

__device__ __forceinline__ bfrag8 pack8(float4 x0, float4 x1) {
    bfrag8 o;
    o[0] = (short)f2bf(x0.x); o[1] = (short)f2bf(x0.y);
    o[2] = (short)f2bf(x0.z); o[3] = (short)f2bf(x0.w);
    o[4] = (short)f2bf(x1.x); o[5] = (short)f2bf(x1.y);
    o[6] = (short)f2bf(x1.z); o[7] = (short)f2bf(x1.w);
    return o;
}

// ---------------------------------------------------------------------------
// K0: weight prep with kappa shuffle for ALL matrices.
//   kappa(kt,lg,j) = 32*kt + 16*(j>>2) + 4*lg + (j&3)
//   o[n*256 + kt*32 + lg*8 + j] = bf16(w[kappa * N + n])
// ---------------------------------------------------------------------------
__global__ void cvt_all_kernel(const float* __restrict__ w1i, const float* __restrict__ w2i,
                               const float* __restrict__ w1u, const float* __restrict__ w2u,
                               unsigned short* __restrict__ o1i, unsigned short* __restrict__ o2i,
                               unsigned short* __restrict__ o1u, unsigned short* __restrict__ o2u) {
    int id = blockIdx.x * 256 + threadIdx.x;        // 0..196607
    const float* w; unsigned short* o; int local; int N;
    if (id < 65536)       { w = w1i; o = o1i; N = 256; local = id; }
    else if (id < 98304)  { w = w2i; o = o2i; N = 128; local = id - 65536; }
    else if (id < 163840) { w = w1u; o = o1u; N = 256; local = id - 98304; }
    else                  { w = w2u; o = o2u; N = 128; local = id - 163840; }
    int n  = local >> 8;
    int r  = local & 255;
    int kt = r >> 5, lg = (r >> 3) & 3, j = r & 7;
    int k  = 32 * kt + 16 * (j >> 2) + 4 * lg + (j & 3);
    o[local] = f2bf(w[(size_t)k * N + n]);
}

// ---------------------------------------------------------------------------
// L1: h = relu([srcA||srcB] @ W1 + b1), kappa-packed bf16 out.
// Swapped GEMM; lane owns full h rows. W1 in LDS with 528-B row stride:
// the +16B pad gives the same 8-slot bank spread as an XOR swizzle, but read
// addresses become laneBase + nt*8448 + kt*64 — COMPILE-TIME IMMEDIATES off
// 2 base registers. (The XOR form had 128 loop-invariant addresses that the
// compiler hoisted into registers, blowing past the 256-VGPR cap and spilling
// ~30 regs/thread -> the 562 MB FETCH / 176 MB WRITE seen in round 8.)
// Prefetch buffer halved: a4[8] reused for text batch (packed after kt=3,
// when af[0..3] is dead) and gcn batch (issued mid-GEMM, packed after the
// h-store). Peak live ~140 regs.
// ---------------------------------------------------------------------------
#define LOAD_TEXT(tt) do { \
    int r_ = (tt) * 16 + lr; \
    int ra_ = rowIdxA ? rowIdxA[r_] : r_; \
    const char* p_ = (const char*)(srcA + (size_t)ra_ * 128) + lg * 16; \
    _Pragma("unroll") \
    for (int c_ = 0; c_ < 8; ++c_) a4[c_] = *(const float4*)(p_ + c_ * 64); \
    } while (0)

#define LOAD_GCN(tt) do { \
    int r_ = (tt) * 16 + lr; \
    const char* p_ = (const char*)(srcB + (size_t)r_ * 128) + lg * 16; \
    _Pragma("unroll") \
    for (int c_ = 0; c_ < 8; ++c_) a4[c_] = *(const float4*)(p_ + c_ * 64); \
    } while (0)

#define STORE_H() do { \
    char* hrow = (char*)hOut + (size_t)(t * 16 + lr) * 512 + lg * 16; \
    _Pragma("unroll") \
    for (int p = 0; p < 8; ++p) { \
        ffrag4 lo = acc1[2 * p], hi = acc1[2 * p + 1]; \
        bfrag8 hb; \
        hb[0] = (short)f2bf(fmaxf(lo[0], 0.f)); \
        hb[1] = (short)f2bf(fmaxf(lo[1], 0.f)); \
        hb[2] = (short)f2bf(fmaxf(lo[2], 0.f)); \
        hb[3] = (short)f2bf(fmaxf(lo[3], 0.f)); \
        hb[4] = (short)f2bf(fmaxf(hi[0], 0.f)); \
        hb[5] = (short)f2bf(fmaxf(hi[1], 0.f)); \
        hb[6] = (short)f2bf(fmaxf(hi[2], 0.f)); \
        hb[7] = (short)f2bf(fmaxf(hi[3], 0.f)); \
        *(bfrag8*)(hrow + p * 64) = hb; \
    } } while (0)

__global__ __launch_bounds__(256, 1) void tower_l1_kernel(
    const float* __restrict__ srcA, const float* __restrict__ srcB,
    const int* __restrict__ rowIdxA,
    const unsigned short* __restrict__ w1s, const float* __restrict__ b1,
    unsigned short* __restrict__ hOut, int nTiles)
{
    __shared__ __align__(16) char smem[135168 + 1024];   // W1 [256][528] + b1
    char* sW1 = smem;
    float* sB1 = (float*)(smem + 135168);

    const int tid  = threadIdx.x;
    const int lane = tid & 63;
    const int wv   = tid >> 6;          // 0..3
    const int lr   = lane & 15;
    const int lg   = lane >> 4;

    {   // stage W1: chunk c -> row n=c>>5, granule m16=c&31 at n*528 + m16*16
        const uint4* g = (const uint4*)w1s;
#pragma unroll
        for (int i = 0; i < 32; ++i) {
            int c = tid + 256 * i;              // 8192 chunks of 16B
            int n = c >> 5, m16 = c & 31;
            *(uint4*)(sW1 + n * 528 + m16 * 16) = g[c];
        }
        sB1[tid] = b1[tid];
    }
    __syncthreads();                            // only barrier

    // lane-invariant bases; all W1/bias reads are base + compile-time imm
    const char* wb0 = sW1 + lr * 528 + lg * 16;             // nt 0..7
    const char* wb1 = wb0 + 8 * 8448;                       // nt 8..15
    const float* bbase = sB1 + lg * 4;

    const int stride = (int)gridDim.x * 4;
    int t = (int)blockIdx.x * 4 + wv;
    if (t >= nTiles) return;

    float4 a4[8];
    bfrag8 af[8];
    // prologue: load+pack tile t, then start text prefetch of t+stride
    LOAD_TEXT(t);
#pragma unroll
    for (int c = 0; c < 4; ++c) af[c] = pack8(a4[2 * c], a4[2 * c + 1]);
    LOAD_GCN(t);
#pragma unroll
    for (int c = 0; c < 4; ++c) af[4 + c] = pack8(a4[2 * c], a4[2 * c + 1]);
    if (t + stride < nTiles) LOAD_TEXT(t + stride);

    for (; t < nTiles; t += stride) {
        const int tn = t + stride;

        ffrag4 acc1[16];
#pragma unroll
        for (int nt = 0; nt < 16; ++nt)
            acc1[nt] = *(const ffrag4*)(bbase + nt * 16);

#pragma unroll
        for (int kt = 0; kt < 4; ++kt) {
#pragma unroll
            for (int nt = 0; nt < 16; ++nt) {
                const char* wb = (nt < 8) ? wb0 : wb1;
                bfrag8 w1f = *(const bfrag8*)(wb + (nt & 7) * 8448 + kt * 64);
                acc1[nt] = mfma16(w1f, af[kt], acc1[nt]);
            }
        }

        // pack next-tile text (af[0..3] dead now), issue next-tile gcn
#pragma unroll
        for (int c = 0; c < 4; ++c) af[c] = pack8(a4[2 * c], a4[2 * c + 1]);
        if (tn < nTiles) LOAD_GCN(tn);

#pragma unroll
        for (int kt = 4; kt < 8; ++kt) {
#pragma unroll
            for (int nt = 0; nt < 16; ++nt) {
                const char* wb = (nt < 8) ? wb0 : wb1;
                bfrag8 w1f = *(const bfrag8*)(wb + (nt & 7) * 8448 + kt * 64);
                acc1[nt] = mfma16(w1f, af[kt], acc1[nt]);
            }
        }

        STORE_H();

        // pack next-tile gcn, issue text for t+2*stride
#pragma unroll
        for (int c = 0; c < 4; ++c) af[4 + c] = pack8(a4[2 * c], a4[2 * c + 1]);
        if (tn + stride < nTiles) LOAD_TEXT(tn + stride);
    }
}

// ---------------------------------------------------------------------------
// L2: y = h @ W2 + b2, L2-normalized. IN-PLACE: hIn (kappa-packed bf16
// [rows][256]) aliases out (f32 [rows][128]); each row fully read to regs by
// its owning wave before overwrite. W2 in LDS, 528-B row stride (immediate
// offsets, same rationale as L1). LDS 68 KB -> 2 blocks/CU.
// ---------------------------------------------------------------------------
__global__ __launch_bounds__(256, 2) void tower_l2_kernel(
    const unsigned short* hIn,               // aliases out — no restrict!
    const unsigned short* __restrict__ w2s, const float* __restrict__ b2,
    float* out, unsigned short* __restrict__ mirror, int nTiles)
{
    __shared__ __align__(16) char smem2[67584 + 512];    // W2 [128][528] + b2
    char* sW2 = smem2;
    float* sB2 = (float*)(smem2 + 67584);

    const int tid  = threadIdx.x;
    const int lane = tid & 63;
    const int wv   = tid >> 6;          // 0..3
    const int lr   = lane & 15;
    const int lg   = lane >> 4;

    {   // stage W2: 4096 chunks of 16B at n*528 + m16*16
        const uint4* g = (const uint4*)w2s;
#pragma unroll
        for (int i = 0; i < 16; ++i) {
            int c = tid + 256 * i;
            int n = c >> 5, m16 = c & 31;
            *(uint4*)(sW2 + n * 528 + m16 * 16) = g[c];
        }
        if (tid < 128) sB2[tid] = b2[tid];
    }
    __syncthreads();                           // only barrier

    const char* wb = sW2 + lr * 528 + lg * 16;
    const float* bbase = sB2 + lg * 4;

    const int stride = (int)gridDim.x * 4;
    for (int t = (int)blockIdx.x * 4 + wv; t < nTiles; t += stride) {
        // load h row (kappa-packed): 8 x 16B at row*512 + kt*64 + lg*16
        const char* hrow = (const char*)hIn + (size_t)(t * 16 + lr) * 512 + lg * 16;
        bfrag8 hf[8];
#pragma unroll
        for (int kt = 0; kt < 8; ++kt)
            hf[kt] = *(const bfrag8*)(hrow + kt * 64);

        ffrag4 acc2[8];
#pragma unroll
        for (int ot = 0; ot < 8; ++ot)
            acc2[ot] = *(const ffrag4*)(bbase + ot * 16);   // bias init
#pragma unroll
        for (int kt = 0; kt < 8; ++kt) {
#pragma unroll
            for (int ot = 0; ot < 8; ++ot) {
                bfrag8 w2f = *(const bfrag8*)(wb + ot * 8448 + kt * 64);
                acc2[ot] = mfma16(w2f, hf[kt], acc2[ot]);
            }
        }

        // lane-local norm: lane holds y[row t*16+lr][ot*16+4lg+q]
        float psum = 0.f;
#pragma unroll
        for (int ot = 0; ot < 8; ++ot)
#pragma unroll
            for (int r = 0; r < 4; ++r) psum += acc2[ot][r] * acc2[ot][r];
        psum += __shfl_xor(psum, 16);
        psum += __shfl_xor(psum, 32);
        float sc = 1.f / fmaxf(sqrtf(psum), 1e-12f);

        int m = t * 16 + lr;
        float* orow = out + (size_t)m * 128 + lg * 4;
#pragma unroll
        for (int ot = 0; ot < 8; ++ot) {
            float4 v4;
            v4.x = acc2[ot][0] * sc; v4.y = acc2[ot][1] * sc;
            v4.z = acc2[ot][2] * sc; v4.w = acc2[ot][3] * sc;
            *(float4*)(orow + ot * 16) = v4;    // 64 B/row per instruction
            if (mirror) {
                uint2 mm;
                mm.x = (unsigned)f2bf(v4.x) | ((unsigned)f2bf(v4.y) << 16);
                mm.y = (unsigned)f2bf(v4.z) | ((unsigned)f2bf(v4.w) << 16);
                *(uint2*)(mirror + (size_t)m * 128 + ot * 16 + 4 * lg) = mm;
            }
        }
    }
}

// ---------------------------------------------------------------------------
// Pool: per-user segment mean. 4 waves/block, 1 user/wave, 2 items/iter.
// ---------------------------------------------------------------------------
__global__ __launch_bounds__(256) void pool3_kernel(
    const unsigned short* __restrict__ mirror,
    const float* __restrict__ itemF,
    const int* __restrict__ histItems,
    const int* __restrict__ histSeg,
    float* __restrict__ hist)
{
    const int u = blockIdx.x * 4 + (threadIdx.x >> 6);
    const int lane = threadIdx.x & 63;
    const int half = lane >> 5;
    const int c = lane & 31;

    int lo = 0, hi = N_HIST;
    while (lo < hi) { int m = (lo + hi) >> 1; if (histSeg[m] < u) lo = m + 1; else hi = m; }
    const int s = lo;
    hi = N_HIST;
    while (lo < hi) { int m = (lo + hi) >> 1; if (histSeg[m] < u + 1) lo = m + 1; else hi = m; }
    const int e = lo;

    float s0 = 0.f, s1 = 0.f, s2 = 0.f, s3 = 0.f;
    if (mirror) {
        for (int i = s + half; i < e; i += 2) {
            int idx = histItems[i];
            uint2 v = *(const uint2*)(mirror + (size_t)idx * 128 + c * 4);
            union { unsigned u; float f; } a, b, cc, d;
            a.u  = v.x << 16; b.u  = v.x & 0xffff0000u;
            cc.u = v.y << 16; d.u  = v.y & 0xffff0000u;
            s0 += a.f; s1 += b.f; s2 += cc.f; s3 += d.f;
        }
    } else {
        for (int i = s + half; i < e; i += 2) {
            int idx = histItems[i];
            float4 v = *(const float4*)(itemF + (size_t)idx * 128 + c * 4);
            s0 += v.x; s1 += v.y; s2 += v.z; s3 += v.w;
        }
    }
    s0 += __shfl_xor(s0, 32);
    s1 += __shfl_xor(s1, 32);
    s2 += __shfl_xor(s2, 32);
    s3 += __shfl_xor(s3, 32);
    if (half == 0) {
        float inv = (e > s) ? 1.f / (float)(e - s) : 0.f;
        float4 r; r.x = s0 * inv; r.y = s1 * inv; r.z = s2 * inv; r.w = s3 * inv;
        *(float4*)(hist + (size_t)u * 128 + c * 4) = r;
    }
}

// ---------------------------------------------------------------------------
extern "C" void kernel_launch(void* const* d_in, const int* in_sizes, int n_in,
                              void* d_out, int out_size, void* d_ws, size_t ws_size,
                              hipStream_t stream) {
    const float* text    = (const float*)d_in[0];
    const float* gcnItem = (const float*)d_in[1];
    const float* gcnUser = (const float*)d_in[2];
    const float* w1i = (const float*)d_in[3];
    const float* b1i = (const float*)d_in[4];
    const float* w2i = (const float*)d_in[5];
    const float* b2i = (const float*)d_in[6];
    const float* w1u = (const float*)d_in[7];
    const float* b1u = (const float*)d_in[8];
    const float* w2u = (const float*)d_in[9];
    const float* b2u = (const float*)d_in[10];
    const int* users     = (const int*)d_in[11];
    const int* histItems = (const int*)d_in[12];
    const int* histSeg   = (const int*)d_in[13];

    float* outUser = (float*)d_out;                          // [16384][128] f32
    float* outItem = (float*)d_out + (size_t)N_USERS * 128;  // [200000][128] f32
    // h buffers live IN-PLACE in the output regions (same byte size per row)
    unsigned short* hItem = (unsigned short*)outItem;        // kappa-packed
    unsigned short* hUser = (unsigned short*)outUser;

    char* ws = (char*)d_ws;
    unsigned short* w1si = (unsigned short*)(ws + 0);        // 131072 B
    unsigned short* w2si = (unsigned short*)(ws + 131072);   // 65536 B
    unsigned short* w1su = (unsigned short*)(ws + 196608);   // 131072 B
    unsigned short* w2su = (unsigned short*)(ws + 327680);   // 65536 B
    float*          hist = (float*)(ws + 393216);            // 8388608 B
    const size_t mirrorOff = 8781824;
    const size_t needBytes = mirrorOff + (size_t)N_ITEMS * 128 * 2;
    unsigned short* mirror = (ws_size >= needBytes) ? (unsigned short*)(ws + mirrorOff) : nullptr;

    cvt_all_kernel<<<768, 256, 0, stream>>>(w1i, w2i, w1u, w2u, w1si, w2si, w1su, w2su);

    // items: L1 (kappa-h into outItem region) -> L2 (in-place finalize + mirror)
    tower_l1_kernel<<<256, 256, 0, stream>>>(
        text, gcnItem, nullptr, w1si, b1i, hItem, N_ITEMS / 16);
    tower_l2_kernel<<<512, 256, 0, stream>>>(
        hItem, w2si, b2i, outItem, mirror, N_ITEMS / 16);

    pool3_kernel<<<N_USERS / 4, 256, 0, stream>>>(mirror, outItem, histItems, histSeg, hist);

    // users: gather gcn_user rows via `users`, concat with hist
    tower_l1_kernel<<<256, 256, 0, stream>>>(
        gcnUser, hist, users, w1su, b1u, hUser, N_USERS / 16);
    tower_l2_kernel<<<128, 256, 0, stream>>>(
        hUser, w2su, b2u, outUser, nullptr, N_USERS / 16);
}